// Round 6
// baseline (91.361 us; speedup 1.0000x reference)
//
#include <hip/hip_runtime.h>
#include <math.h>

#define BB 8
#define CC 512
#define HWSZ 6400
#define NN 100
#define HR 40
#define WR 40
#define VV 20        // N_CLASSES_FG
#define VO 21        // BG + FG
#define TPX 128      // pixels per tile
#define NT (HWSZ / TPX)      // 50 tiles per batch image

typedef unsigned long long u64;

// order-preserving float -> uint32 map (min float == min uint)
__device__ __forceinline__ unsigned mapf(float f) {
    unsigned b = __float_as_uint(f);
    return (b & 0x80000000u) ? ~b : (b | 0x80000000u);
}

// ---------------- K1: normalized prototypes [c][v]; init batchMin + cnt -----
__global__ __launch_bounds__(512) void k_protos(const float* __restrict__ refc,
                                                const int* __restrict__ coord,
                                                const int* __restrict__ cls,
                                                float* __restrict__ protosT,
                                                u64* __restrict__ batchMin,
                                                unsigned* __restrict__ cnt) {
    const int v = blockIdx.x;        // class
    const int c = threadIdx.x;       // channel
    if (v == 0 && c < BB) { batchMin[c] = ~0ull; cnt[c] = 0u; }

    float acc = 0.f;
    int n_in_cls = 0;
    for (int n = 0; n < NN; ++n) {
        if (cls[n] == v) {           // uniform across block
            int y = coord[2 * n + 1];
            int x = coord[2 * n + 0];
            acc += refc[((size_t)(n * CC + c) * HR + y) * WR + x];
            ++n_in_cls;
        }
    }
    acc /= fmaxf((float)n_in_cls, 1.0f);

    float ss = acc * acc;
    #pragma unroll
    for (int off = 32; off; off >>= 1) ss += __shfl_xor(ss, off);
    __shared__ float sW[8];
    const int wave = c >> 6, lane = c & 63;
    if (lane == 0) sW[wave] = ss;
    __syncthreads();
    float tot = 0.f;
    #pragma unroll
    for (int w = 0; w < 8; ++w) tot += sW[w];
    float scale = 1.0f / fmaxf(sqrtf(tot), 1e-10f);

    protosT[c * VV + v] = acc * scale;   // transposed for scalar loads
}

// ---------------- K2: prob_C + argmin + (last block) minvec -----------------
// grid = 8b x 50 tiles(128 px); block = 256 = 4 waves.
// Wave w owns channels [w*128, w*128+128) (wave-uniform -> protos via s_load);
// lane owns pixel pair 2*lane. float2 global loads, 512B runs.
__global__ __launch_bounds__(256) void k_probC(const float* __restrict__ codeC,
                                               const float* __restrict__ codeBG,
                                               const float* __restrict__ protosT,
                                               float* __restrict__ probC,
                                               u64* __restrict__ batchMin,
                                               unsigned* __restrict__ cnt,
                                               float* __restrict__ minvecN) {
    __shared__ float red[4 * 21 * TPX];   // 43 KB: [wave][ss,d0..d19][px]
    __shared__ float sScale[TPX];
    __shared__ u64 sKey[2];
    __shared__ int sLast;
    __shared__ unsigned sPix;
    __shared__ float sR[4];

    const int tid  = threadIdx.x;
    const int w    = tid >> 6, lane = tid & 63;
    const int b    = blockIdx.x / NT;
    const int tile = blockIdx.x % NT;
    const int c0   = __builtin_amdgcn_readfirstlane(w * 128);

    const float* src = codeC + ((size_t)(b * CC + c0)) * HWSZ + tile * TPX + 2 * lane;
    const float* pt  = protosT + (size_t)c0 * VV;   // wave-uniform -> s_load

    float2 d[VV];
    #pragma unroll
    for (int v = 0; v < VV; ++v) d[v] = make_float2(0.f, 0.f);
    float2 ss = make_float2(0.f, 0.f);

    #pragma unroll 16
    for (int i = 0; i < 128; ++i) {
        float2 x = *(const float2*)(src + (size_t)i * HWSZ);
        ss.x = fmaf(x.x, x.x, ss.x);
        ss.y = fmaf(x.y, x.y, ss.y);
        const float* pr = pt + i * VV;
        #pragma unroll
        for (int v = 0; v < VV; ++v) {
            float p = pr[v];
            d[v].x = fmaf(x.x, p, d[v].x);
            d[v].y = fmaf(x.y, p, d[v].y);
        }
    }

    // cross-wave reduce: rows = {ss, d0..d19} per wave
    *(float2*)&red[(w * 21 + 0) * TPX + 2 * lane] = ss;
    #pragma unroll
    for (int v = 0; v < VV; ++v)
        *(float2*)&red[(w * 21 + 1 + v) * TPX + 2 * lane] = d[v];
    __syncthreads();

    for (int q = tid; q < 21 * TPX; q += 256) {
        float t = red[q] + red[21 * TPX + q] + red[42 * TPX + q] + red[63 * TPX + q];
        red[q] = t;   // in-place into wave-0 region; q classes disjoint per thread
    }
    __syncthreads();
    if (tid < TPX) sScale[tid] = 1.0f / fmaxf(sqrtf(red[tid]), 1e-10f);
    __syncthreads();

    // store probC (scaled)
    float* dst = probC + (size_t)b * VV * HWSZ + tile * TPX;
    for (int q = tid; q < VV * TPX; q += 256) {
        int v = q >> 7, px = q & (TPX - 1);
        dst[(size_t)v * HWSZ + px] = red[TPX + q] * sScale[px];
    }

    // per-pixel sum -> deterministic argmin key
    if (tid < TPX) {
        float psum = 0.f;
        #pragma unroll
        for (int v = 0; v < VV; ++v) psum += red[(1 + v) * TPX + tid];
        psum *= sScale[tid];
        u64 key = ((u64)mapf(psum) << 32) | (unsigned)(tile * TPX + tid);
        #pragma unroll
        for (int off = 32; off; off >>= 1) {
            u64 o = __shfl_xor(key, off);
            if (o < key) key = o;
        }
        if (lane == 0) sKey[w] = key;
    }
    __syncthreads();
    if (tid == 0) {
        u64 kk = sKey[0] < sKey[1] ? sKey[0] : sKey[1];
        atomicMin(&batchMin[b], kk);
        __threadfence();
        unsigned old = atomicAdd(&cnt[b], 1u);
        sLast = (old == NT - 1) ? 1 : 0;
    }
    __syncthreads();

    // last block of this batch computes the normalized min_vec
    if (sLast) {
        if (tid == 0) {
            __threadfence();
            u64 kk = atomicMin(&batchMin[b], ~0ull);   // identity RMW = coherent read
            sPix = (unsigned)(kk & 0xFFFFFFFFull);
        }
        __syncthreads();
        const int pix = (int)sPix;
        float x0 = codeBG[((size_t)(b * CC + tid)) * HWSZ + pix];
        float x1 = codeBG[((size_t)(b * CC + 256 + tid)) * HWSZ + pix];
        float s2 = fmaf(x0, x0, x1 * x1);
        #pragma unroll
        for (int off = 32; off; off >>= 1) s2 += __shfl_xor(s2, off);
        if (lane == 0) sR[w] = s2;
        __syncthreads();
        float totq = sR[0] + sR[1] + sR[2] + sR[3];
        float sc = 1.0f / fmaxf(sqrtf(totq), 1e-10f);
        minvecN[b * CC + tid] = x0 * sc;
        minvecN[b * CC + 256 + tid] = x1 * sc;
    }
}

// ---------------- K3: prob_BG + fused softmax + output ----------------------
// Same 4-wave x 128-channel float2 structure; min_vec via scalar loads.
__global__ __launch_bounds__(256) void k_bg_softmax(const float* __restrict__ codeBG,
                                                    const float* __restrict__ minvecN,
                                                    const float* __restrict__ probC,
                                                    float* __restrict__ out) {
    __shared__ float red2[4 * 2 * TPX];   // 4 KB: [wave][{ss,dg}][px]

    const int tid  = threadIdx.x;
    const int w    = tid >> 6, lane = tid & 63;
    const int b    = blockIdx.x / NT;
    const int tile = blockIdx.x % NT;
    const int c0   = __builtin_amdgcn_readfirstlane(w * 128);

    const float* src = codeBG + ((size_t)(b * CC + c0)) * HWSZ + tile * TPX + 2 * lane;
    const float* mv  = minvecN + b * CC + c0;   // wave-uniform -> s_load

    float2 ss = make_float2(0.f, 0.f), dg = make_float2(0.f, 0.f);
    #pragma unroll 16
    for (int i = 0; i < 128; ++i) {
        float2 x = *(const float2*)(src + (size_t)i * HWSZ);
        float m = mv[i];
        ss.x = fmaf(x.x, x.x, ss.x);
        ss.y = fmaf(x.y, x.y, ss.y);
        dg.x = fmaf(x.x, m, dg.x);
        dg.y = fmaf(x.y, m, dg.y);
    }
    *(float2*)&red2[(w * 2 + 0) * TPX + 2 * lane] = ss;
    *(float2*)&red2[(w * 2 + 1) * TPX + 2 * lane] = dg;
    __syncthreads();
    {
        int q = tid;   // 256 threads cover 2*TPX exactly
        float t = red2[q] + red2[2 * TPX + q] + red2[4 * TPX + q] + red2[6 * TPX + q];
        red2[q] = t;
    }
    __syncthreads();

    if (tid < TPX) {
        const int px = tid;
        float pbg = red2[TPX + px] * (1.0f / fmaxf(sqrtf(red2[px]), 1e-10f));

        float pv[VO];
        pv[0] = pbg;
        const float* pc = probC + (size_t)b * VV * HWSZ + tile * TPX + px;
        #pragma unroll
        for (int v = 0; v < VV; ++v) pv[v + 1] = pc[(size_t)v * HWSZ];

        float m = pv[0];
        #pragma unroll
        for (int i = 1; i < VO; ++i) m = fmaxf(m, pv[i]);
        float se = 0.f;
        #pragma unroll
        for (int i = 0; i < VO; ++i) { pv[i] = __expf(pv[i] - m); se += pv[i]; }
        float inv = 1.0f / se;

        float* dstp = out + (size_t)b * VO * HWSZ + tile * TPX + px;
        #pragma unroll
        for (int i = 0; i < VO; ++i) dstp[(size_t)i * HWSZ] = pv[i] * inv;
    }
}

extern "C" void kernel_launch(void* const* d_in, const int* in_sizes, int n_in,
                              void* d_out, int out_size, void* d_ws, size_t ws_size,
                              hipStream_t stream) {
    const float* codeC  = (const float*)d_in[0];
    const float* codeBG = (const float*)d_in[1];
    const float* refc   = (const float*)d_in[2];
    // d_in[3] (ref_code_bg) unused by the reference
    const int* coord = (const int*)d_in[4];
    const int* cls   = (const int*)d_in[5];
    float* out = (float*)d_out;

    char* ws = (char*)d_ws;
    float*    protosT  = (float*)   (ws);             // 40,960 B  [c][v]
    float*    probC    = (float*)   (ws + 40960);     // 4,096,000 B
    float*    minvecN  = (float*)   (ws + 4136960);   // 16,384 B
    u64*      batchMin = (u64*)     (ws + 4153344);   // 64 B
    unsigned* cnt      = (unsigned*)(ws + 4153408);   // 32 B

    k_protos    <<<dim3(VV),      dim3(512), 0, stream>>>(refc, coord, cls, protosT, batchMin, cnt);
    k_probC     <<<dim3(BB * NT), dim3(256), 0, stream>>>(codeC, codeBG, protosT, probC, batchMin, cnt, minvecN);
    k_bg_softmax<<<dim3(BB * NT), dim3(256), 0, stream>>>(codeBG, minvecN, probC, out);
}